// Round 9
// baseline (201.889 us; speedup 1.0000x reference)
//
#include <hip/hip_runtime.h>

typedef __attribute__((ext_vector_type(8))) short short8;  // 8 bf16 (4 VGPRs)
typedef __attribute__((ext_vector_type(4))) float f32x4;   // MFMA 16x16 accum

#define NUM_IDS 65
#define EDIM 32
#define NSUM (NUM_IDS * EDIM)      // 2080 per-label-dim sums
#define NTOT (NSUM + NUM_IDS)      // 2145 = sums + counts
#define LPAD 33                    // padded row for k3/k4 LDS tiles
#define ROWS 34                    // per-label row: 32 sums + count + pad
#define COPYSZ 2212                // 65*34=2210 -> pad even

// ws layout (float offsets)
#define WS_MEANS   0               // 2080
#define WS_COEF    2080            // 65
#define WS_SUMS    2145            // 2145 (2080 sums then 65 counts)
#define WS_PUSH    4290
#define WS_REG     4291
#define WS_CF      4292
#define WS_C       4293
#define WS_PULLACC 4294
#define WS_PART    4352            // per-block partials [nb1][NTOT]

__global__ void k0_zero(float* __restrict__ ws) {
    int i = blockIdx.x * 256 + threadIdx.x;
    if (i < NTOT) ws[WS_SUMS + i] = 0.f;
}

__device__ inline short f2bf(float f) {          // fp32 -> bf16 bits, RNE
    unsigned u = __float_as_uint(f);
    unsigned r = (u + 0x7FFFu + ((u >> 16) & 1u)) >> 16;
    return (short)r;
}

// Pass 1 as MFMA: sums[32 dims][80 labels-padded] += emb_chunk^T · onehot,
// counts via a ones-row A-tile. Per wave: 32-point chunks, wave-private LDS
// staging (no barriers), 15 MFMA per chunk, single flush at end.
__global__ __launch_bounds__(256) void k1_reduce(const float4* __restrict__ emb4,
                                                 const int* __restrict__ lab,
                                                 float* __restrict__ ws,
                                                 int M, int nb1, int atomic_mode) {
    __shared__ float ls[4 * COPYSZ];             // 4 wave-private regions, 35.4 KB
    __shared__ alignas(16) int labls[4][32];
    const int t = threadIdx.x;
    const int wave = t >> 6;
    const int lane = t & 63;
    const int q = lane >> 4;                     // lane quarter (k-block)
    const int c = lane & 15;                     // row (A) / col (B,D) index
    float* my = ls + wave * COPYSZ;
    int* mylab = labls[wave];

    f32x4 acc[3][5];
    #pragma unroll
    for (int a = 0; a < 3; ++a)
        #pragma unroll
        for (int b = 0; b < 5; ++b)
            acc[a][b] = (f32x4)0.f;

    short8 A2;                                   // ones-row tile (row 0 = 1.0)
    #pragma unroll
    for (int i = 0; i < 8; ++i) A2[i] = (c == 0) ? (short)0x3F80 : (short)0;

    const long totalChunks = ((long)M + 31) / 32;
    const long cstride = (long)nb1 * 4;
    for (long ch = (long)blockIdx.x * 4 + wave; ch < totalChunks; ch += cstride) {
        const long base = ch * 32;               // first point of chunk
        // ---- stage 32 pts x 32 fp32 -> my[pt*34 + d] (coalesced float4) ----
        const float4* src = emb4 + base * 8;     // 8 float4 per point
        #pragma unroll
        for (int j = 0; j < 4; ++j) {
            int flat = j * 64 + lane;            // float4 slot in chunk (0..255)
            int pt = flat >> 3, sub = flat & 7;
            float4 v = make_float4(0.f, 0.f, 0.f, 0.f);
            if (base + pt < M) v = src[flat];
            float* dst = my + pt * ROWS + sub * 4;
            *(float2*)(dst)     = make_float2(v.x, v.y);
            *(float2*)(dst + 2) = make_float2(v.z, v.w);
        }
        if (lane < 32) {
            long pp = base + lane;
            mylab[lane] = (pp < M) ? lab[pp] : 0;
        }
        __builtin_amdgcn_sched_barrier(0);       // keep ds_reads after ds_writes

        // ---- A fragments: A[row=c][k=q*8+i] = embT = staged[k][c] ----
        short8 A0, A1;
        #pragma unroll
        for (int i = 0; i < 8; ++i) {
            int k = q * 8 + i;
            A0[i] = f2bf(my[k * ROWS + c]);
            A1[i] = f2bf(my[k * ROWS + 16 + c]);
        }
        int4 laA = *(const int4*)(mylab + q * 8);
        int4 laB = *(const int4*)(mylab + q * 8 + 4);
        int lv[8] = {laA.x, laA.y, laA.z, laA.w, laB.x, laB.y, laB.z, laB.w};

        // ---- B one-hot per label-tile + 3 MFMA ----
        #pragma unroll
        for (int nt = 0; nt < 5; ++nt) {
            short8 B;
            #pragma unroll
            for (int i = 0; i < 8; ++i)
                B[i] = (lv[i] == nt * 16 + c) ? (short)0x3F80 : (short)0;
            acc[0][nt] = __builtin_amdgcn_mfma_f32_16x16x32_bf16(A0, B, acc[0][nt], 0, 0, 0);
            acc[1][nt] = __builtin_amdgcn_mfma_f32_16x16x32_bf16(A1, B, acc[1][nt], 0, 0, 0);
            acc[2][nt] = __builtin_amdgcn_mfma_f32_16x16x32_bf16(A2, B, acc[2][nt], 0, 0, 0);
        }
    }

    // ---- flush: zero my region, write tiles (bijective), block-combine ----
    for (int j = lane; j < COPYSZ; j += 64) my[j] = 0.f;
    __builtin_amdgcn_sched_barrier(0);
    #pragma unroll
    for (int rt = 0; rt < 3; ++rt)
        #pragma unroll
        for (int nt = 0; nt < 5; ++nt)
            #pragma unroll
            for (int r = 0; r < 4; ++r) {
                int row = q * 4 + r;             // D row = (lane>>4)*4 + reg
                int lbl = nt * 16 + c;           // D col = lane&15
                if (rt < 2) {
                    if (lbl < NUM_IDS) my[lbl * ROWS + rt * 16 + row] = acc[rt][nt][r];
                } else {
                    if (row == 0 && lbl < NUM_IDS) my[lbl * ROWS + 32] = acc[2][nt][r];
                }
            }
    __syncthreads();

    for (int j = t; j < NTOT; j += 256) {
        int off = (j < NSUM) ? ((j >> 5) * ROWS + (j & 31))
                             : ((j - NSUM) * ROWS + 32);
        float v = ls[off] + ls[COPYSZ + off] + ls[2 * COPYSZ + off] + ls[3 * COPYSZ + off];
        if (atomic_mode) {
            if (v != 0.f) atomicAdd(&ws[WS_SUMS + j], v);
        } else {
            ws[WS_PART + (size_t)blockIdx.x * NTOT + j] = v;
        }
    }
}

// Reduce per-block partials: each block handles 32 consecutive j.
__global__ __launch_bounds__(256) void k2_reduce_partials(float* __restrict__ ws, int nb1) {
    const int t = threadIdx.x;
    const int jl = t & 31, bl = t >> 5;
    const int j = blockIdx.x * 32 + jl;
    const float* part = ws + WS_PART;
    float acc = 0.f;
    if (j < NTOT)
        for (int b = bl; b < nb1; b += 8) acc += part[(size_t)b * NTOT + j];
    __shared__ float red[256];
    red[t] = acc;
    __syncthreads();
    for (int sdown = 128; sdown >= 32; sdown >>= 1) {
        if (t < sdown) red[t] += red[t + sdown];
        __syncthreads();
    }
    if (t < 32) {
        int jj = blockIdx.x * 32 + t;
        if (jj < NTOT) ws[WS_SUMS + jj] = red[t];
    }
}

// Means, present mask, C, push loss, reg loss, coef; zero pull accumulator.
__global__ __launch_bounds__(256) void k3_finalize(float* __restrict__ ws) {
    __shared__ float lmean[NUM_IDS * LPAD];
    __shared__ float lcnt[NUM_IDS];
    __shared__ int   lpres[NUM_IDS];
    __shared__ float red[256];
    __shared__ float red2[256];
    const int t = threadIdx.x;
    const float* sg = ws + WS_SUMS;

    if (t < NUM_IDS) {
        float cv = sg[NSUM + t];
        lcnt[t] = cv;
        lpres[t] = (t > 0 && cv > 0.f) ? 1 : 0;
    }
    __syncthreads();

    for (int j = t; j < NSUM; j += 256) {
        int cc = j >> 5, e = j & 31;
        float m = sg[j] / fmaxf(lcnt[cc], 1.f);
        ws[WS_MEANS + j] = m;
        lmean[cc * LPAD + e] = m;
    }
    if (t < NUM_IDS) ws[WS_COEF + t] = lpres[t] ? (1.f / fmaxf(lcnt[t], 1.f)) : 0.f;
    __syncthreads();

    float psum = 0.f;
    for (int pi = t; pi < 2080; pi += 256) {
        int i = 0, rem = pi;
        while (rem >= NUM_IDS - 1 - i) { rem -= NUM_IDS - 1 - i; ++i; }
        int jj = i + 1 + rem;
        if (lpres[i] && lpres[jj]) {
            float d2 = 0.f;
            #pragma unroll
            for (int e = 0; e < EDIM; ++e) {
                float d = lmean[i * LPAD + e] - lmean[jj * LPAD + e];
                d2 += d * d;
            }
            float pd = sqrtf(d2);
            float h = fmaxf(2.0f * 1.5f - pd, 0.f);  // 2*DELTA_PUSH = 3.0
            psum += h * h;
        }
    }
    float rsum = 0.f;
    if (t < NUM_IDS && lpres[t]) {
        float m2 = 0.f;
        #pragma unroll
        for (int e = 0; e < EDIM; ++e) { float m = lmean[t * LPAD + e]; m2 += m * m; }
        rsum = sqrtf(m2);
    }
    red[t] = psum; red2[t] = rsum;
    __syncthreads();
    for (int sdown = 128; sdown > 0; sdown >>= 1) {
        if (t < sdown) { red[t] += red[t + sdown]; red2[t] += red2[t + sdown]; }
        __syncthreads();
    }
    if (t == 0) {
        int C = 0;
        for (int cc = 1; cc < NUM_IDS; ++cc) C += lpres[cc];
        float Cf = fmaxf((float)C, 1.f);
        long np = (long)C * (C - 1) / 2;
        ws[WS_PUSH] = (np > 0) ? red[0] / (float)np : 0.f;
        ws[WS_REG]  = red2[0] / Cf;
        ws[WS_CF]   = Cf;
        ws[WS_C]    = (float)C;
        ws[WS_PULLACC] = 0.f;
    }
}

// Pass 2: hinged pull distances; ping-pong pipelined loads.
__global__ __launch_bounds__(256) void k4_pull(const float4* __restrict__ emb4,
                                               const int* __restrict__ lab,
                                               float* __restrict__ ws,
                                               int M, int nb4) {
    __shared__ float lmean[NUM_IDS * LPAD];
    __shared__ float lcoef[NUM_IDS];
    __shared__ float lpull[NUM_IDS];
    __shared__ float red[NUM_IDS];
    const int t = threadIdx.x;
    for (int j = t; j < NSUM; j += 256) lmean[(j >> 5) * LPAD + (j & 31)] = ws[WS_MEANS + j];
    if (t < NUM_IDS) { lcoef[t] = ws[WS_COEF + t]; lpull[t] = 0.f; }
    __syncthreads();

    const int c = t & 7;
    const long stride = (long)nb4 * 32;
    const long start = (long)blockIdx.x * 32 + (t >> 3);

    auto LD = [&](long p, int& L, float4& v) {
        if (p < M) { L = lab[p]; v = emb4[p * 8 + c]; }
        else       { L = 0; v = make_float4(0.f, 0.f, 0.f, 0.f); }
    };
    auto PR = [&](int L, float4 v) {
        float d2 = 0.f;
        if (L > 0) {
            int bse = L * LPAD + c * 4;
            float dx = v.x - lmean[bse + 0];
            float dy = v.y - lmean[bse + 1];
            float dz = v.z - lmean[bse + 2];
            float dw = v.w - lmean[bse + 3];
            d2 = dx * dx + dy * dy + dz * dz + dw * dw;
        }
        d2 += __shfl_xor(d2, 1);
        d2 += __shfl_xor(d2, 2);
        d2 += __shfl_xor(d2, 4);
        if (c == 0 && L > 0 && d2 > 0.f) {
            float dist = sqrtf(d2);
            float h = fmaxf(dist - 0.5f, 0.f);   // DELTA_PULL = 0.5
            atomicAdd(&lpull[L], h * h);
        }
    };

    int L0, L1;
    float4 v0, v1;
    long pA = start;
    LD(pA, L0, v0);
    while (pA < M) {
        const long pB = pA + stride;
        LD(pB, L1, v1);
        PR(L0, v0);
        const long pA2 = pB + stride;
        LD(pA2, L0, v0);
        PR(L1, v1);
        pA = pA2;
    }
    __syncthreads();
    if (t < NUM_IDS) red[t] = lpull[t] * lcoef[t];
    __syncthreads();
    if (t == 0) {
        float sacc = 0.f;
        for (int cc = 1; cc < NUM_IDS; ++cc) sacc += red[cc];
        atomicAdd(&ws[WS_PULLACC], sacc);
    }
}

__global__ void k5_final(const float* __restrict__ ws, float* __restrict__ out) {
    if (threadIdx.x == 0) {
        float C = ws[WS_C];
        float total = 0.f;
        if (C > 0.f) {
            total = ws[WS_PULLACC] / ws[WS_CF]   // ALPHA = 1
                  + ws[WS_PUSH]                  // BETA = 1
                  + 0.001f * ws[WS_REG];         // GAMMA = 0.001
        }
        out[0] = total;
    }
}

extern "C" void kernel_launch(void* const* d_in, const int* in_sizes, int n_in,
                              void* d_out, int out_size, void* d_ws, size_t ws_size,
                              hipStream_t stream) {
    const float4* emb4 = (const float4*)d_in[0];
    const int* lab = (const int*)d_in[1];
    float* ws = (float*)d_ws;
    float* out = (float*)d_out;
    const int M = in_sizes[1];

    long ws_floats = (long)(ws_size / 4);
    long avail = ws_floats - WS_PART - 64;
    int nb1 = (int)(avail / NTOT);
    if (nb1 > 1024) nb1 = 1024;
    int atomic_mode = (nb1 < 8) ? 1 : 0;
    if (atomic_mode) {
        nb1 = 1024;
        k0_zero<<<dim3(9), dim3(256), 0, stream>>>(ws);
    }

    k1_reduce<<<dim3(nb1), dim3(256), 0, stream>>>(emb4, lab, ws, M, nb1, atomic_mode);
    if (!atomic_mode)
        k2_reduce_partials<<<dim3((NTOT + 31) / 32), dim3(256), 0, stream>>>(ws, nb1);
    k3_finalize<<<dim3(1), dim3(256), 0, stream>>>(ws);
    const int nb4 = 2048;
    k4_pull<<<dim3(nb4), dim3(256), 0, stream>>>(emb4, lab, ws, M, nb4);
    k5_final<<<dim3(1), dim3(64), 0, stream>>>(ws, out);
}